// Round 12
// baseline (2998.539 us; speedup 1.0000x reference)
//
#include <hip/hip_runtime.h>
#include <cstdint>

#define NB 128
#define NT 512
#define NL 512
#define NH 512
#define NU 512

// 2*log2(e): tanh(x) = 1 - 2/(exp2(K2E*x)+1); exp2 hoisted into the GEMM epilogue.
static constexpr float K2E = 2.8853900817779268f;

// ---------------------------------------------------------------- K0: sum(V)+bV
__global__ __launch_bounds__(256) void k_sumv(const float* __restrict__ V,
                                              const float* __restrict__ bV,
                                              float* __restrict__ svbv) {
  __shared__ float red[256];
  int tid = threadIdx.x;
  red[tid] = V[tid] + V[tid + 256];
  __syncthreads();
  for (int off = 128; off > 0; off >>= 1) {
    if (tid < off) red[tid] += red[tid + off];
    __syncthreads();
  }
  if (tid == 0) svbv[0] = red[0] + bV[0];
}

// --------------------------------------- K1/K2: out = exp2(K2E*(A@W + bias))
// R12: register prefetch of chunk k+1 issued BEFORE compute of chunk k (R5/R8
// pattern); bl/bh loaded just-in-time per k-row; k-quad loop not unrolled to
// keep natural VGPR lean. No launch_bounds occupancy arg (R6/R7 standing rule).
__global__ __launch_bounds__(256) void k_proj_exp(const float* __restrict__ A,
                                                  const float* __restrict__ W,
                                                  const float* __restrict__ bias,
                                                  float* __restrict__ out) {
  __shared__ float As[128 * 32];   // swizzled 16B granules, row stride 128B
  __shared__ float Ws[32 * 132];   // padded stride 132 floats
  const int tid = threadIdx.x;
  const int m0 = blockIdx.y * 128;
  const int n0 = blockIdx.x * 128;
  const int i = tid & 15;
  const int j = tid >> 4;
  const int ga = tid & 7, mra = tid >> 3;   // A staging: granule, row
  const int gw = tid & 31, kw = tid >> 5;   // W staging: granule, row

  float acc[8][8];
#pragma unroll
  for (int a = 0; a < 8; ++a)
#pragma unroll
    for (int b = 0; b < 8; ++b) acc[a][b] = 0.f;

  float4 pa[4], pw[4];
  // prologue: stage chunk 0 into regs, commit to LDS
#pragma unroll
  for (int q = 0; q < 4; ++q) {
    pa[q] = *(const float4*)(A + (size_t)(m0 + mra + 32 * q) * NH + 4 * ga);
    pw[q] = *(const float4*)(W + (size_t)(kw + 8 * q) * NU + n0 + 4 * gw);
  }
#pragma unroll
  for (int q = 0; q < 4; ++q) {
    int row = mra + 32 * q;
    *(float4*)(As + row * 32 + 4 * (ga ^ ((row ^ (row >> 3)) & 7))) = pa[q];
    *(float4*)(Ws + (kw + 8 * q) * 132 + 4 * gw) = pw[q];
  }
  __syncthreads();

#pragma unroll 1
  for (int kci = 0; kci < 16; ++kci) {
    // issue next chunk's global loads first (latency hides under compute)
    if (kci < 15) {
      const int kc = (kci + 1) * 32;
#pragma unroll
      for (int q = 0; q < 4; ++q) {
        pa[q] = *(const float4*)(A + (size_t)(m0 + mra + 32 * q) * NH + kc + 4 * ga);
        pw[q] = *(const float4*)(W + (size_t)(kc + kw + 8 * q) * NU + n0 + 4 * gw);
      }
    }
#pragma unroll 1
    for (int k4 = 0; k4 < 32; k4 += 4) {
      const int gk = k4 >> 2;
      float4 a4[8];
#pragma unroll
      for (int r = 0; r < 8; ++r) {
        int row = 8 * i + r;
        a4[r] = *(const float4*)(As + row * 32 + 4 * (gk ^ ((row ^ (row >> 3)) & 7)));
      }
#pragma unroll
      for (int r = 0; r < 4; ++r) {
        float4 bl = *(const float4*)(Ws + (k4 + r) * 132 + 8 * j);
        float4 bh = *(const float4*)(Ws + (k4 + r) * 132 + 8 * j + 4);
        float bv[8] = {bl.x, bl.y, bl.z, bl.w, bh.x, bh.y, bh.z, bh.w};
#pragma unroll
        for (int a = 0; a < 8; ++a) {
          float av = ((const float*)&a4[a])[r];
#pragma unroll
          for (int b = 0; b < 8; ++b) acc[a][b] = fmaf(av, bv[b], acc[a][b]);
        }
      }
    }
    __syncthreads();   // compute on this chunk done (uniform trip count)
    if (kci < 15) {
#pragma unroll
      for (int q = 0; q < 4; ++q) {
        int row = mra + 32 * q;
        *(float4*)(As + row * 32 + 4 * (ga ^ ((row ^ (row >> 3)) & 7))) = pa[q];
        *(float4*)(Ws + (kw + 8 * q) * 132 + 4 * gw) = pw[q];
      }
      __syncthreads(); // writes visible (uniform)
    }
  }
#pragma unroll
  for (int a = 0; a < 8; ++a) {
    size_t orow = (size_t)(m0 + 8 * i + a) * NU + n0 + 8 * j;
#pragma unroll
    for (int b = 0; b < 8; b += 4) {
      float4 ov;
      ov.x = __builtin_amdgcn_exp2f(K2E * (acc[a][b + 0] + bias[n0 + 8 * j + b + 0]));
      ov.y = __builtin_amdgcn_exp2f(K2E * (acc[a][b + 1] + bias[n0 + 8 * j + b + 1]));
      ov.z = __builtin_amdgcn_exp2f(K2E * (acc[a][b + 2] + bias[n0 + 8 * j + b + 2]));
      ov.w = __builtin_amdgcn_exp2f(K2E * (acc[a][b + 3] + bias[n0 + 8 * j + b + 3]));
      *(float4*)(out + orow + b) = ov;
    }
  }
}

// ---------------------------------------------- K3: S[b,t,l] = base - 2*sum_u V*rc
// R10 version (best measured: ~1.60 ms, VGPR 68): octet fraction tree
// (29 VALU + acc-fma + 1 rcp / 8 elems), single-buffered 16.4 KB LDS,
// 2 uniform barriers/chunk, V via wave-uniform scalar loads.
__global__ __launch_bounds__(256) void k_score(const float* __restrict__ Ed,
                                               const float* __restrict__ Ee,
                                               const float* __restrict__ Vv,
                                               const float* __restrict__ svbv,
                                               float* __restrict__ out) {
  __shared__ float dpl[64 * 32];   // 8 KB, swizzled 16B granules
  __shared__ float epl[64 * 32];   // 8 KB
  const int tid = threadIdx.x;
  const int b = blockIdx.z;
  const int t0 = blockIdx.y * 64;
  const int l0 = blockIdx.x * 64;
  const int ti = tid & 15;          // t micro group (4 rows)
  const int lj = tid >> 4;          // l micro group (4 cols)
  const int tt = tid & 63;          // staging row
  const int g0 = (tid >> 6) * 2;    // staging granules g0, g0+1
  const float* Edb = Ed + ((size_t)b * NT + t0) * NU;
  const float* Eeb = Ee + ((size_t)b * NL + l0) * NU;
  const int sw = (tt ^ (tt >> 3)) & 7;
  const int pos0 = tt * 32 + 4 * ((g0 + 0) ^ sw);
  const int pos1 = tt * 32 + 4 * ((g0 + 1) ^ sw);
  const size_t srow = (size_t)tt * NU;

  float acc[4][4];
#pragma unroll
  for (int a = 0; a < 4; ++a)
#pragma unroll
    for (int c = 0; c < 4; ++c) acc[a][c] = 0.f;

  // prologue: stage chunk 0
  {
    float4 d0 = *(const float4*)(Edb + srow + 4 * g0);
    float4 d1 = *(const float4*)(Edb + srow + 4 * g0 + 4);
    float4 e0 = *(const float4*)(Eeb + srow + 4 * g0);
    float4 e1 = *(const float4*)(Eeb + srow + 4 * g0 + 4);
    *(float4*)(dpl + pos0) = d0;
    *(float4*)(dpl + pos1) = d1;
    *(float4*)(epl + pos0) = e0;
    *(float4*)(epl + pos1) = e1;
  }
  __syncthreads();

#pragma unroll 1
  for (int c = 0; c < 16; ++c) {
    // issue next-chunk global loads first (latency hidden under compute)
    float4 pd0, pd1, pe0, pe1;
    if (c < 15) {
      const int uc = (c + 1) * 32;
      pd0 = *(const float4*)(Edb + srow + uc + 4 * g0);
      pd1 = *(const float4*)(Edb + srow + uc + 4 * g0 + 4);
      pe0 = *(const float4*)(Eeb + srow + uc + 4 * g0);
      pe1 = *(const float4*)(Eeb + srow + uc + 4 * g0 + 4);
    }
#pragma unroll 1
    for (int g8 = 0; g8 < 4; ++g8) {
      // wave-uniform V loads -> scalar (SGPR) operands
      const float* vb = Vv + c * 32 + g8 * 8;
      const float v0 = vb[0], v1 = vb[1], v2 = vb[2], v3 = vb[3];
      const float v4_ = vb[4], v5 = vb[5], v6 = vb[6], v7 = vb[7];
      float4 bLo[4], bHi[4];
#pragma unroll
      for (int r = 0; r < 4; ++r) {
        int rowb = 4 * lj + r;
        int swb = (rowb ^ (rowb >> 3)) & 7;
        bLo[r] = *(const float4*)(epl + rowb * 32 + 4 * ((2 * g8 + 0) ^ swb));
        bHi[r] = *(const float4*)(epl + rowb * 32 + 4 * ((2 * g8 + 1) ^ swb));
      }
#pragma unroll
      for (int a = 0; a < 4; ++a) {
        int rowa = 4 * ti + a;
        int swa = (rowa ^ (rowa >> 3)) & 7;
        float4 aLo = *(const float4*)(dpl + rowa * 32 + 4 * ((2 * g8 + 0) ^ swa));
        float4 aHi = *(const float4*)(dpl + rowa * 32 + 4 * ((2 * g8 + 1) ^ swa));
#pragma unroll
        for (int cc = 0; cc < 4; ++cc) {
          const float* bp = (const float*)&bLo[cc];
          const float* bh = (const float*)&bHi[cc];
          float d0 = fmaf(aLo.x, bp[0], 1.0f);
          float d1 = fmaf(aLo.y, bp[1], 1.0f);
          float d2 = fmaf(aLo.z, bp[2], 1.0f);
          float d3 = fmaf(aLo.w, bp[3], 1.0f);
          float d4 = fmaf(aHi.x, bh[0], 1.0f);
          float d5 = fmaf(aHi.y, bh[1], 1.0f);
          float d6 = fmaf(aHi.z, bh[2], 1.0f);
          float d7 = fmaf(aHi.w, bh[3], 1.0f);
          float d01 = d0 * d1, d23 = d2 * d3, d45 = d4 * d5, d67 = d6 * d7;
          float n01 = fmaf(v0, d1, v1 * d0);
          float n23 = fmaf(v2, d3, v3 * d2);
          float n45 = fmaf(v4_, d5, v5 * d4);
          float n67 = fmaf(v6, d7, v7 * d6);
          float n03 = fmaf(n01, d23, n23 * d01);
          float d03 = d01 * d23;
          float n47 = fmaf(n45, d67, n67 * d45);
          float d47 = d45 * d67;
          float num = fmaf(n03, d47, n47 * d03);
          float den = d03 * d47;
          acc[a][cc] = fmaf(num, __builtin_amdgcn_rcpf(den), acc[a][cc]);
        }
      }
    }
    __syncthreads();   // all reads of this chunk done (uniform trip count)
    if (c < 15) {
      *(float4*)(dpl + pos0) = pd0;
      *(float4*)(dpl + pos1) = pd1;
      *(float4*)(epl + pos0) = pe0;
      *(float4*)(epl + pos1) = pe1;
      __syncthreads(); // writes visible (uniform)
    }
  }

  const float base = svbv[0];  // sum(V) + bV
#pragma unroll
  for (int a = 0; a < 4; ++a) {
    size_t orow = ((size_t)b * NT + t0 + 4 * ti + a) * NL + l0 + 4 * lj;
    float4 ov;
    ov.x = base - 2.f * acc[a][0];
    ov.y = base - 2.f * acc[a][1];
    ov.z = base - 2.f * acc[a][2];
    ov.w = base - 2.f * acc[a][3];
    *(float4*)(out + orow) = ov;
  }
}

// ------------------------- K4: sequential mask/softmax/argmax, in-place on d_out
// No max-subtraction: |score| <= sum|V| ~ 18 (e^18 << f32 max); masked entries
// exp(-1e6) = 0 exactly. Argmax chain and sum chain interleaved in one 6-step
// shuffle loop.
__global__ __launch_bounds__(64) void k_seq(float* __restrict__ out) {
  const int b = blockIdx.x;
  const int lane = threadIdx.x;
  float* base = out + (size_t)b * NT * NL;
  float maskf[8];
#pragma unroll
  for (int k = 0; k < 8; ++k) maskf[k] = 0.f;
  float cur[8];
#pragma unroll
  for (int k = 0; k < 8; ++k) cur[k] = base[lane + 64 * k];

  for (int t = 0; t < NT; ++t) {
    float nxt[8] = {0.f, 0.f, 0.f, 0.f, 0.f, 0.f, 0.f, 0.f};
    if (t + 1 < NT) {
      const float* nr = base + (size_t)(t + 1) * NL;
#pragma unroll
      for (int k = 0; k < 8; ++k) nxt[k] = nr[lane + 64 * k];
    }
    float e[8];
    float psum = 0.f;
    float mval = -3.4e38f;
    int midx = 0x7fffffff;
#pragma unroll
    for (int k = 0; k < 8; ++k) {
      float v = cur[k] - maskf[k] * 1000000.0f;
      e[k] = __expf(v);          // masked -> exp(-1e6) = 0 exactly
      psum += e[k];
      int idx = lane + 64 * k;
      if (v > mval || (v == mval && idx < midx)) { mval = v; midx = idx; }
    }
#pragma unroll
    for (int off = 32; off > 0; off >>= 1) {
      float ov = __shfl_xor(mval, off);
      int oi = __shfl_xor(midx, off);
      float ps = __shfl_xor(psum, off);
      psum += ps;
      if (ov > mval || (ov == mval && oi < midx)) { mval = ov; midx = oi; }
    }
    const float inv = 1.0f / psum;
    float* orow = base + (size_t)t * NL;
#pragma unroll
    for (int k = 0; k < 8; ++k) orow[lane + 64 * k] = e[k] * inv;
#pragma unroll
    for (int k = 0; k < 8; ++k)
      if (lane + 64 * k == midx) maskf[k] += 1.0f;
#pragma unroll
    for (int k = 0; k < 8; ++k) cur[k] = nxt[k];
  }
}

extern "C" void kernel_launch(void* const* d_in, const int* in_sizes, int n_in,
                              void* d_out, int out_size, void* d_ws, size_t ws_size,
                              hipStream_t stream) {
  const float* dec_outputs = (const float*)d_in[0];  // [B,T,H]
  const float* enc_outputs = (const float*)d_in[1];  // [B,L,H]
  const float* W1 = (const float*)d_in[3];
  const float* b1 = (const float*)d_in[4];
  const float* W2 = (const float*)d_in[5];
  const float* b2 = (const float*)d_in[6];
  const float* V  = (const float*)d_in[7];
  const float* bV = (const float*)d_in[8];
  float* out = (float*)d_out;  // [B,T,L] f32

  // workspace: [svbv pad 256B][Ed 134MB][Ee 134MB]
  float* svbv = (float*)d_ws;
  float* Ed = (float*)((char*)d_ws + 256);
  float* Ee = Ed + (size_t)NB * NT * NU;

  hipLaunchKernelGGL(k_sumv, dim3(1), dim3(256), 0, stream, V, bV, svbv);
  hipLaunchKernelGGL(k_proj_exp, dim3(NU / 128, (NB * NT) / 128), dim3(256), 0, stream,
                     dec_outputs, W1, b1, Ed);
  hipLaunchKernelGGL(k_proj_exp, dim3(NU / 128, (NB * NL) / 128), dim3(256), 0, stream,
                     enc_outputs, W2, b2, Ee);
  hipLaunchKernelGGL(k_score, dim3(NL / 64, NT / 64, NB), dim3(256), 0, stream,
                     Ed, Ee, V, svbv, out);
  hipLaunchKernelGGL(k_seq, dim3(NB), dim3(64), 0, stream, out);
}

// Round 13
// 2721.816 us; speedup vs baseline: 1.1017x; 1.1017x over previous
//
#include <hip/hip_runtime.h>
#include <cstdint>

#define NB 128
#define NT 512
#define NL 512
#define NH 512
#define NU 512

// 2*log2(e): tanh(x) = 1 - 2/(exp2(K2E*x)+1); exp2 hoisted into the GEMM epilogue.
static constexpr float K2E = 2.8853900817779268f;

// ---------------------------------------------------------------- K0: sum(V)+bV
__global__ __launch_bounds__(256) void k_sumv(const float* __restrict__ V,
                                              const float* __restrict__ bV,
                                              float* __restrict__ svbv) {
  __shared__ float red[256];
  int tid = threadIdx.x;
  red[tid] = V[tid] + V[tid + 256];
  __syncthreads();
  for (int off = 128; off > 0; off >>= 1) {
    if (tid < off) red[tid] += red[tid + off];
    __syncthreads();
  }
  if (tid == 0) svbv[0] = red[0] + bV[0];
}

// --------------------------------------- K1/K2: out = exp2(K2E*(A@W + bias))
// R10 version (measured best ~0.44 ms each): stage -> barrier -> compute.
// TLP across ~3 resident blocks already covers staging latency; R12's explicit
// prefetch + unroll-1 regressed it (don't hand-pipeline what TLP covers).
__global__ __launch_bounds__(256) void k_proj_exp(const float* __restrict__ A,
                                                  const float* __restrict__ W,
                                                  const float* __restrict__ bias,
                                                  float* __restrict__ out) {
  __shared__ float As[128 * 32];   // swizzled 16B granules, row stride 128B
  __shared__ float Ws[32 * 132];   // padded stride 132 floats
  const int tid = threadIdx.x;
  const int m0 = blockIdx.y * 128;
  const int n0 = blockIdx.x * 128;
  const int i = tid & 15;
  const int j = tid >> 4;
  const int ga = tid & 7, mra = tid >> 3;
  const int gw = tid & 31, kw = tid >> 5;

  float acc[8][8];
#pragma unroll
  for (int a = 0; a < 8; ++a)
#pragma unroll
    for (int b = 0; b < 8; ++b) acc[a][b] = 0.f;

  for (int kc = 0; kc < NH; kc += 32) {
#pragma unroll
    for (int q = 0; q < 4; ++q) {
      int row = mra + 32 * q;
      float4 av = *(const float4*)(A + (size_t)(m0 + row) * NH + kc + 4 * ga);
      int pos = ga ^ ((row ^ (row >> 3)) & 7);
      *(float4*)(As + row * 32 + 4 * pos) = av;
    }
#pragma unroll
    for (int q = 0; q < 4; ++q) {
      int row = kw + 8 * q;
      float4 wv = *(const float4*)(W + (size_t)(kc + row) * NU + n0 + 4 * gw);
      *(float4*)(Ws + row * 132 + 4 * gw) = wv;
    }
    __syncthreads();
#pragma unroll
    for (int k4 = 0; k4 < 32; k4 += 4) {
      const int gk = k4 >> 2;
      float4 a4[8];
      float4 bl[4], bh[4];
#pragma unroll
      for (int r = 0; r < 8; ++r) {
        int row = 8 * i + r;
        a4[r] = *(const float4*)(As + row * 32 + 4 * (gk ^ ((row ^ (row >> 3)) & 7)));
      }
#pragma unroll
      for (int r = 0; r < 4; ++r) {
        bl[r] = *(const float4*)(Ws + (k4 + r) * 132 + 8 * j);
        bh[r] = *(const float4*)(Ws + (k4 + r) * 132 + 8 * j + 4);
      }
#pragma unroll
      for (int r = 0; r < 4; ++r) {
        float bv[8] = {bl[r].x, bl[r].y, bl[r].z, bl[r].w,
                       bh[r].x, bh[r].y, bh[r].z, bh[r].w};
#pragma unroll
        for (int a = 0; a < 8; ++a) {
          float av = ((const float*)&a4[a])[r];
#pragma unroll
          for (int b = 0; b < 8; ++b) acc[a][b] = fmaf(av, bv[b], acc[a][b]);
        }
      }
    }
    __syncthreads();
  }
#pragma unroll
  for (int a = 0; a < 8; ++a) {
    size_t orow = (size_t)(m0 + 8 * i + a) * NU + n0 + 8 * j;
#pragma unroll
    for (int b = 0; b < 8; b += 4) {
      float4 ov;
      ov.x = __builtin_amdgcn_exp2f(K2E * (acc[a][b + 0] + bias[n0 + 8 * j + b + 0]));
      ov.y = __builtin_amdgcn_exp2f(K2E * (acc[a][b + 1] + bias[n0 + 8 * j + b + 1]));
      ov.z = __builtin_amdgcn_exp2f(K2E * (acc[a][b + 2] + bias[n0 + 8 * j + b + 2]));
      ov.w = __builtin_amdgcn_exp2f(K2E * (acc[a][b + 3] + bias[n0 + 8 * j + b + 3]));
      *(float4*)(out + orow + b) = ov;
    }
  }
}

// ---------------------------------------------- K3: S[b,t,l] = base - 2*sum_u V*rc
// R10 version (measured best ~1.60 ms, VGPR 68, VALUBusy 91%): octet fraction
// tree (29 VALU + acc-fma + 1 rcp / 8 elems), single-buffered 16.4 KB LDS,
// 2 uniform barriers/chunk, V via wave-uniform scalar loads.
__global__ __launch_bounds__(256) void k_score(const float* __restrict__ Ed,
                                               const float* __restrict__ Ee,
                                               const float* __restrict__ Vv,
                                               const float* __restrict__ svbv,
                                               float* __restrict__ out) {
  __shared__ float dpl[64 * 32];   // 8 KB, swizzled 16B granules
  __shared__ float epl[64 * 32];   // 8 KB
  const int tid = threadIdx.x;
  const int b = blockIdx.z;
  const int t0 = blockIdx.y * 64;
  const int l0 = blockIdx.x * 64;
  const int ti = tid & 15;          // t micro group (4 rows)
  const int lj = tid >> 4;          // l micro group (4 cols)
  const int tt = tid & 63;          // staging row
  const int g0 = (tid >> 6) * 2;    // staging granules g0, g0+1
  const float* Edb = Ed + ((size_t)b * NT + t0) * NU;
  const float* Eeb = Ee + ((size_t)b * NL + l0) * NU;
  const int sw = (tt ^ (tt >> 3)) & 7;
  const int pos0 = tt * 32 + 4 * ((g0 + 0) ^ sw);
  const int pos1 = tt * 32 + 4 * ((g0 + 1) ^ sw);
  const size_t srow = (size_t)tt * NU;

  float acc[4][4];
#pragma unroll
  for (int a = 0; a < 4; ++a)
#pragma unroll
    for (int c = 0; c < 4; ++c) acc[a][c] = 0.f;

  // prologue: stage chunk 0
  {
    float4 d0 = *(const float4*)(Edb + srow + 4 * g0);
    float4 d1 = *(const float4*)(Edb + srow + 4 * g0 + 4);
    float4 e0 = *(const float4*)(Eeb + srow + 4 * g0);
    float4 e1 = *(const float4*)(Eeb + srow + 4 * g0 + 4);
    *(float4*)(dpl + pos0) = d0;
    *(float4*)(dpl + pos1) = d1;
    *(float4*)(epl + pos0) = e0;
    *(float4*)(epl + pos1) = e1;
  }
  __syncthreads();

#pragma unroll 1
  for (int c = 0; c < 16; ++c) {
    // issue next-chunk global loads first (latency hidden under compute)
    float4 pd0, pd1, pe0, pe1;
    if (c < 15) {
      const int uc = (c + 1) * 32;
      pd0 = *(const float4*)(Edb + srow + uc + 4 * g0);
      pd1 = *(const float4*)(Edb + srow + uc + 4 * g0 + 4);
      pe0 = *(const float4*)(Eeb + srow + uc + 4 * g0);
      pe1 = *(const float4*)(Eeb + srow + uc + 4 * g0 + 4);
    }
#pragma unroll 1
    for (int g8 = 0; g8 < 4; ++g8) {
      // wave-uniform V loads -> scalar (SGPR) operands
      const float* vb = Vv + c * 32 + g8 * 8;
      const float v0 = vb[0], v1 = vb[1], v2 = vb[2], v3 = vb[3];
      const float v4_ = vb[4], v5 = vb[5], v6 = vb[6], v7 = vb[7];
      float4 bLo[4], bHi[4];
#pragma unroll
      for (int r = 0; r < 4; ++r) {
        int rowb = 4 * lj + r;
        int swb = (rowb ^ (rowb >> 3)) & 7;
        bLo[r] = *(const float4*)(epl + rowb * 32 + 4 * ((2 * g8 + 0) ^ swb));
        bHi[r] = *(const float4*)(epl + rowb * 32 + 4 * ((2 * g8 + 1) ^ swb));
      }
#pragma unroll
      for (int a = 0; a < 4; ++a) {
        int rowa = 4 * ti + a;
        int swa = (rowa ^ (rowa >> 3)) & 7;
        float4 aLo = *(const float4*)(dpl + rowa * 32 + 4 * ((2 * g8 + 0) ^ swa));
        float4 aHi = *(const float4*)(dpl + rowa * 32 + 4 * ((2 * g8 + 1) ^ swa));
#pragma unroll
        for (int cc = 0; cc < 4; ++cc) {
          const float* bp = (const float*)&bLo[cc];
          const float* bh = (const float*)&bHi[cc];
          float d0 = fmaf(aLo.x, bp[0], 1.0f);
          float d1 = fmaf(aLo.y, bp[1], 1.0f);
          float d2 = fmaf(aLo.z, bp[2], 1.0f);
          float d3 = fmaf(aLo.w, bp[3], 1.0f);
          float d4 = fmaf(aHi.x, bh[0], 1.0f);
          float d5 = fmaf(aHi.y, bh[1], 1.0f);
          float d6 = fmaf(aHi.z, bh[2], 1.0f);
          float d7 = fmaf(aHi.w, bh[3], 1.0f);
          float d01 = d0 * d1, d23 = d2 * d3, d45 = d4 * d5, d67 = d6 * d7;
          float n01 = fmaf(v0, d1, v1 * d0);
          float n23 = fmaf(v2, d3, v3 * d2);
          float n45 = fmaf(v4_, d5, v5 * d4);
          float n67 = fmaf(v6, d7, v7 * d6);
          float n03 = fmaf(n01, d23, n23 * d01);
          float d03 = d01 * d23;
          float n47 = fmaf(n45, d67, n67 * d45);
          float d47 = d45 * d67;
          float num = fmaf(n03, d47, n47 * d03);
          float den = d03 * d47;
          acc[a][cc] = fmaf(num, __builtin_amdgcn_rcpf(den), acc[a][cc]);
        }
      }
    }
    __syncthreads();   // all reads of this chunk done (uniform trip count)
    if (c < 15) {
      *(float4*)(dpl + pos0) = pd0;
      *(float4*)(dpl + pos1) = pd1;
      *(float4*)(epl + pos0) = pe0;
      *(float4*)(epl + pos1) = pe1;
      __syncthreads(); // writes visible (uniform)
    }
  }

  const float base = svbv[0];  // sum(V) + bV
#pragma unroll
  for (int a = 0; a < 4; ++a) {
    size_t orow = ((size_t)b * NT + t0 + 4 * ti + a) * NL + l0 + 4 * lj;
    float4 ov;
    ov.x = base - 2.f * acc[a][0];
    ov.y = base - 2.f * acc[a][1];
    ov.z = base - 2.f * acc[a][2];
    ov.w = base - 2.f * acc[a][3];
    *(float4*)(out + orow) = ov;
  }
}

// ------------------------- K4: sequential mask/softmax/argmax, in-place on d_out
// No max-subtraction: |score| <= sum|V| ~ 18 (e^18 << f32 max); masked entries
// exp(-1e6) = 0 exactly. Argmax chain and sum chain interleaved in one 6-step
// shuffle loop.
__global__ __launch_bounds__(64) void k_seq(float* __restrict__ out) {
  const int b = blockIdx.x;
  const int lane = threadIdx.x;
  float* base = out + (size_t)b * NT * NL;
  float maskf[8];
#pragma unroll
  for (int k = 0; k < 8; ++k) maskf[k] = 0.f;
  float cur[8];
#pragma unroll
  for (int k = 0; k < 8; ++k) cur[k] = base[lane + 64 * k];

  for (int t = 0; t < NT; ++t) {
    float nxt[8] = {0.f, 0.f, 0.f, 0.f, 0.f, 0.f, 0.f, 0.f};
    if (t + 1 < NT) {
      const float* nr = base + (size_t)(t + 1) * NL;
#pragma unroll
      for (int k = 0; k < 8; ++k) nxt[k] = nr[lane + 64 * k];
    }
    float e[8];
    float psum = 0.f;
    float mval = -3.4e38f;
    int midx = 0x7fffffff;
#pragma unroll
    for (int k = 0; k < 8; ++k) {
      float v = cur[k] - maskf[k] * 1000000.0f;
      e[k] = __expf(v);          // masked -> exp(-1e6) = 0 exactly
      psum += e[k];
      int idx = lane + 64 * k;
      if (v > mval || (v == mval && idx < midx)) { mval = v; midx = idx; }
    }
#pragma unroll
    for (int off = 32; off > 0; off >>= 1) {
      float ov = __shfl_xor(mval, off);
      int oi = __shfl_xor(midx, off);
      float ps = __shfl_xor(psum, off);
      psum += ps;
      if (ov > mval || (ov == mval && oi < midx)) { mval = ov; midx = oi; }
    }
    const float inv = 1.0f / psum;
    float* orow = base + (size_t)t * NL;
#pragma unroll
    for (int k = 0; k < 8; ++k) orow[lane + 64 * k] = e[k] * inv;
#pragma unroll
    for (int k = 0; k < 8; ++k)
      if (lane + 64 * k == midx) maskf[k] += 1.0f;
#pragma unroll
    for (int k = 0; k < 8; ++k) cur[k] = nxt[k];
  }
}

extern "C" void kernel_launch(void* const* d_in, const int* in_sizes, int n_in,
                              void* d_out, int out_size, void* d_ws, size_t ws_size,
                              hipStream_t stream) {
  const float* dec_outputs = (const float*)d_in[0];  // [B,T,H]
  const float* enc_outputs = (const float*)d_in[1];  // [B,L,H]
  const float* W1 = (const float*)d_in[3];
  const float* b1 = (const float*)d_in[4];
  const float* W2 = (const float*)d_in[5];
  const float* b2 = (const float*)d_in[6];
  const float* V  = (const float*)d_in[7];
  const float* bV = (const float*)d_in[8];
  float* out = (float*)d_out;  // [B,T,L] f32

  // workspace: [svbv pad 256B][Ed 134MB][Ee 134MB]
  float* svbv = (float*)d_ws;
  float* Ed = (float*)((char*)d_ws + 256);
  float* Ee = Ed + (size_t)NB * NT * NU;

  hipLaunchKernelGGL(k_sumv, dim3(1), dim3(256), 0, stream, V, bV, svbv);
  hipLaunchKernelGGL(k_proj_exp, dim3(NU / 128, (NB * NT) / 128), dim3(256), 0, stream,
                     dec_outputs, W1, b1, Ed);
  hipLaunchKernelGGL(k_proj_exp, dim3(NU / 128, (NB * NL) / 128), dim3(256), 0, stream,
                     enc_outputs, W2, b2, Ee);
  hipLaunchKernelGGL(k_score, dim3(NL / 64, NT / 64, NB), dim3(256), 0, stream,
                     Ed, Ee, V, svbv, out);
  hipLaunchKernelGGL(k_seq, dim3(NB), dim3(64), 0, stream, out);
}

// Round 14
// 2341.110 us; speedup vs baseline: 1.2808x; 1.1626x over previous
//
#include <hip/hip_runtime.h>
#include <cstdint>

#define NB 128
#define NT 512
#define NL 512
#define NH 512
#define NU 512

// 2*log2(e): tanh(x) = 1 - 2/(exp2(K2E*x)+1); exp2 hoisted into the GEMM epilogue.
static constexpr float K2E = 2.8853900817779268f;

typedef _Float16 h16;
typedef h16 half8 __attribute__((ext_vector_type(8)));
typedef h16 half4 __attribute__((ext_vector_type(4)));
typedef float f32x4 __attribute__((ext_vector_type(4)));

// ---------------------------------------------------------------- K0: sum(V)+bV
__global__ __launch_bounds__(256) void k_sumv(const float* __restrict__ V,
                                              const float* __restrict__ bV,
                                              float* __restrict__ svbv) {
  __shared__ float red[256];
  int tid = threadIdx.x;
  red[tid] = V[tid] + V[tid + 256];
  __syncthreads();
  for (int off = 128; off > 0; off >>= 1) {
    if (tid < off) red[tid] += red[tid + off];
    __syncthreads();
  }
  if (tid == 0) svbv[0] = red[0] + bV[0];
}

// --------------------- K1/K2: out = exp2(K2E*(A@W + bias)) via fp16x3 MFMA
// Split A = Ah + Al, W = Wh + Wl (fp16 hi/lo; 22 mantissa bits combined);
// acc = Ah*Wh + Ah*Wl + Al*Wh (dropped Al*Wl ~ 2^-22 relative -- f32-class).
// 128x128 tile, 4 waves 2x2 (64x64 each), K-step 32, mfma_f32_16x16x32_f16.
// A staged [m][k], W staged TRANSPOSED [n][k] so both frags are contiguous
// b128 reads: lane l holds X[l&15][8*(l>>4)+j]. C/D: col=lane&15,
// row=4*(lane>>4)+reg (guide m89). Row stride 40 fp16 = 80B: 16B-aligned,
// bank step 20 -> 2-way conflicts (free).
#define PSTR 40
__global__ __launch_bounds__(256) void k_proj_mfma(const float* __restrict__ A,
                                                   const float* __restrict__ W,
                                                   const float* __restrict__ bias,
                                                   float* __restrict__ out) {
  __shared__ __align__(16) h16 Ah[128 * PSTR];   // 10 KB each
  __shared__ __align__(16) h16 Al[128 * PSTR];
  __shared__ __align__(16) h16 Bh[128 * PSTR];   // W^T: [n][k]
  __shared__ __align__(16) h16 Bl[128 * PSTR];
  const int tid = threadIdx.x;
  const int m0 = blockIdx.y * 128;
  const int n0 = blockIdx.x * 128;
  const int lane = tid & 63;
  const int wid = tid >> 6;
  const int wm = (wid >> 1) * 64;    // wave m-offset in tile
  const int wn = (wid & 1) * 64;     // wave n-offset in tile
  const int fr = lane & 15;          // fragment row index
  const int fg = lane >> 4;          // fragment k-granule (8 elems)
  // staging indices
  const int ar = tid >> 1, ak = (tid & 1) * 16;      // A: row, k-offset
  const int wk = tid >> 3, wno = (tid & 7) * 16;     // W: k-row, n-offset

  f32x4 acc[4][4];
#pragma unroll
  for (int tm = 0; tm < 4; ++tm)
#pragma unroll
    for (int tn = 0; tn < 4; ++tn) acc[tm][tn] = (f32x4){0.f, 0.f, 0.f, 0.f};

#pragma unroll 1
  for (int kc = 0; kc < 16; ++kc) {
    // ---- stage A tile 128x32 f32 -> fp16 hi/lo, [m][k] layout
#pragma unroll
    for (int q = 0; q < 4; ++q) {
      float4 v = *(const float4*)(A + (size_t)(m0 + ar) * NH + kc * 32 + ak + 4 * q);
      half4 h, l;
      h.x = (h16)v.x; l.x = (h16)(v.x - (float)h.x);
      h.y = (h16)v.y; l.y = (h16)(v.y - (float)h.y);
      h.z = (h16)v.z; l.z = (h16)(v.z - (float)h.z);
      h.w = (h16)v.w; l.w = (h16)(v.w - (float)h.w);
      *(half4*)(Ah + ar * PSTR + ak + 4 * q) = h;
      *(half4*)(Al + ar * PSTR + ak + 4 * q) = l;
    }
    // ---- stage W tile 32x128 f32 -> fp16 hi/lo, TRANSPOSED [n][k] layout
#pragma unroll
    for (int q = 0; q < 4; ++q) {
      float4 v = *(const float4*)(W + (size_t)(kc * 32 + wk) * NU + n0 + wno + 4 * q);
      float vv[4] = {v.x, v.y, v.z, v.w};
#pragma unroll
      for (int i2 = 0; i2 < 4; ++i2) {
        h16 h = (h16)vv[i2];
        h16 l = (h16)(vv[i2] - (float)h);
        int n = wno + 4 * q + i2;
        Bh[n * PSTR + wk] = h;
        Bl[n * PSTR + wk] = l;
      }
    }
    __syncthreads();
    // ---- fragment compute: 48 MFMA per wave per K-step
    half8 bh[4], bl[4];
#pragma unroll
    for (int tn = 0; tn < 4; ++tn) {
      bh[tn] = *(const half8*)(Bh + (wn + tn * 16 + fr) * PSTR + 8 * fg);
      bl[tn] = *(const half8*)(Bl + (wn + tn * 16 + fr) * PSTR + 8 * fg);
    }
#pragma unroll
    for (int tm = 0; tm < 4; ++tm) {
      half8 ah = *(const half8*)(Ah + (wm + tm * 16 + fr) * PSTR + 8 * fg);
      half8 al = *(const half8*)(Al + (wm + tm * 16 + fr) * PSTR + 8 * fg);
#pragma unroll
      for (int tn = 0; tn < 4; ++tn) {
        acc[tm][tn] = __builtin_amdgcn_mfma_f32_16x16x32_f16(ah, bh[tn], acc[tm][tn], 0, 0, 0);
        acc[tm][tn] = __builtin_amdgcn_mfma_f32_16x16x32_f16(ah, bl[tn], acc[tm][tn], 0, 0, 0);
        acc[tm][tn] = __builtin_amdgcn_mfma_f32_16x16x32_f16(al, bh[tn], acc[tm][tn], 0, 0, 0);
      }
    }
    __syncthreads();
  }
  // ---- epilogue: D[row=4*fg+reg][col=fr] per tile; exp2(K2E*(acc+bias))
#pragma unroll
  for (int tn = 0; tn < 4; ++tn) {
    const int gn = n0 + wn + tn * 16 + fr;
    const float bsv = bias[gn];
#pragma unroll
    for (int tm = 0; tm < 4; ++tm) {
#pragma unroll
      for (int rg = 0; rg < 4; ++rg) {
        int gm = m0 + wm + tm * 16 + 4 * fg + rg;
        out[(size_t)gm * NU + gn] =
            __builtin_amdgcn_exp2f(K2E * (acc[tm][tn][rg] + bsv));
      }
    }
  }
}

// ---------------------------------------------- K3: S[b,t,l] = base - 2*sum_u V*rc
// R10/R13 version (measured best ~1.60-1.65 ms, VGPR 68, VALUBusy 91%): octet
// fraction tree (29 VALU + acc-fma + 1 rcp / 8 elems), single-buffered 16.4 KB
// LDS, 2 uniform barriers/chunk, V via wave-uniform scalar loads.
__global__ __launch_bounds__(256) void k_score(const float* __restrict__ Ed,
                                               const float* __restrict__ Ee,
                                               const float* __restrict__ Vv,
                                               const float* __restrict__ svbv,
                                               float* __restrict__ out) {
  __shared__ float dpl[64 * 32];   // 8 KB, swizzled 16B granules
  __shared__ float epl[64 * 32];   // 8 KB
  const int tid = threadIdx.x;
  const int b = blockIdx.z;
  const int t0 = blockIdx.y * 64;
  const int l0 = blockIdx.x * 64;
  const int ti = tid & 15;          // t micro group (4 rows)
  const int lj = tid >> 4;          // l micro group (4 cols)
  const int tt = tid & 63;          // staging row
  const int g0 = (tid >> 6) * 2;    // staging granules g0, g0+1
  const float* Edb = Ed + ((size_t)b * NT + t0) * NU;
  const float* Eeb = Ee + ((size_t)b * NL + l0) * NU;
  const int sw = (tt ^ (tt >> 3)) & 7;
  const int pos0 = tt * 32 + 4 * ((g0 + 0) ^ sw);
  const int pos1 = tt * 32 + 4 * ((g0 + 1) ^ sw);
  const size_t srow = (size_t)tt * NU;

  float acc[4][4];
#pragma unroll
  for (int a = 0; a < 4; ++a)
#pragma unroll
    for (int c = 0; c < 4; ++c) acc[a][c] = 0.f;

  // prologue: stage chunk 0
  {
    float4 d0 = *(const float4*)(Edb + srow + 4 * g0);
    float4 d1 = *(const float4*)(Edb + srow + 4 * g0 + 4);
    float4 e0 = *(const float4*)(Eeb + srow + 4 * g0);
    float4 e1 = *(const float4*)(Eeb + srow + 4 * g0 + 4);
    *(float4*)(dpl + pos0) = d0;
    *(float4*)(dpl + pos1) = d1;
    *(float4*)(epl + pos0) = e0;
    *(float4*)(epl + pos1) = e1;
  }
  __syncthreads();

#pragma unroll 1
  for (int c = 0; c < 16; ++c) {
    // issue next-chunk global loads first (latency hidden under compute)
    float4 pd0, pd1, pe0, pe1;
    if (c < 15) {
      const int uc = (c + 1) * 32;
      pd0 = *(const float4*)(Edb + srow + uc + 4 * g0);
      pd1 = *(const float4*)(Edb + srow + uc + 4 * g0 + 4);
      pe0 = *(const float4*)(Eeb + srow + uc + 4 * g0);
      pe1 = *(const float4*)(Eeb + srow + uc + 4 * g0 + 4);
    }
#pragma unroll 1
    for (int g8 = 0; g8 < 4; ++g8) {
      // wave-uniform V loads -> scalar (SGPR) operands
      const float* vb = Vv + c * 32 + g8 * 8;
      const float v0 = vb[0], v1 = vb[1], v2 = vb[2], v3 = vb[3];
      const float v4_ = vb[4], v5 = vb[5], v6 = vb[6], v7 = vb[7];
      float4 bLo[4], bHi[4];
#pragma unroll
      for (int r = 0; r < 4; ++r) {
        int rowb = 4 * lj + r;
        int swb = (rowb ^ (rowb >> 3)) & 7;
        bLo[r] = *(const float4*)(epl + rowb * 32 + 4 * ((2 * g8 + 0) ^ swb));
        bHi[r] = *(const float4*)(epl + rowb * 32 + 4 * ((2 * g8 + 1) ^ swb));
      }
#pragma unroll
      for (int a = 0; a < 4; ++a) {
        int rowa = 4 * ti + a;
        int swa = (rowa ^ (rowa >> 3)) & 7;
        float4 aLo = *(const float4*)(dpl + rowa * 32 + 4 * ((2 * g8 + 0) ^ swa));
        float4 aHi = *(const float4*)(dpl + rowa * 32 + 4 * ((2 * g8 + 1) ^ swa));
#pragma unroll
        for (int cc = 0; cc < 4; ++cc) {
          const float* bp = (const float*)&bLo[cc];
          const float* bh = (const float*)&bHi[cc];
          float d0 = fmaf(aLo.x, bp[0], 1.0f);
          float d1 = fmaf(aLo.y, bp[1], 1.0f);
          float d2 = fmaf(aLo.z, bp[2], 1.0f);
          float d3 = fmaf(aLo.w, bp[3], 1.0f);
          float d4 = fmaf(aHi.x, bh[0], 1.0f);
          float d5 = fmaf(aHi.y, bh[1], 1.0f);
          float d6 = fmaf(aHi.z, bh[2], 1.0f);
          float d7 = fmaf(aHi.w, bh[3], 1.0f);
          float d01 = d0 * d1, d23 = d2 * d3, d45 = d4 * d5, d67 = d6 * d7;
          float n01 = fmaf(v0, d1, v1 * d0);
          float n23 = fmaf(v2, d3, v3 * d2);
          float n45 = fmaf(v4_, d5, v5 * d4);
          float n67 = fmaf(v6, d7, v7 * d6);
          float n03 = fmaf(n01, d23, n23 * d01);
          float d03 = d01 * d23;
          float n47 = fmaf(n45, d67, n67 * d45);
          float d47 = d45 * d67;
          float num = fmaf(n03, d47, n47 * d03);
          float den = d03 * d47;
          acc[a][cc] = fmaf(num, __builtin_amdgcn_rcpf(den), acc[a][cc]);
        }
      }
    }
    __syncthreads();   // all reads of this chunk done (uniform trip count)
    if (c < 15) {
      *(float4*)(dpl + pos0) = pd0;
      *(float4*)(dpl + pos1) = pd1;
      *(float4*)(epl + pos0) = pe0;
      *(float4*)(epl + pos1) = pe1;
      __syncthreads(); // writes visible (uniform)
    }
  }

  const float base = svbv[0];  // sum(V) + bV
#pragma unroll
  for (int a = 0; a < 4; ++a) {
    size_t orow = ((size_t)b * NT + t0 + 4 * ti + a) * NL + l0 + 4 * lj;
    float4 ov;
    ov.x = base - 2.f * acc[a][0];
    ov.y = base - 2.f * acc[a][1];
    ov.z = base - 2.f * acc[a][2];
    ov.w = base - 2.f * acc[a][3];
    *(float4*)(out + orow) = ov;
  }
}

// ------------------------- K4: sequential mask/softmax/argmax, in-place on d_out
// No max-subtraction: |score| <= sum|V| ~ 18 (e^18 << f32 max); masked entries
// exp(-1e6) = 0 exactly. Argmax chain and sum chain interleaved in one 6-step
// shuffle loop.
__global__ __launch_bounds__(64) void k_seq(float* __restrict__ out) {
  const int b = blockIdx.x;
  const int lane = threadIdx.x;
  float* base = out + (size_t)b * NT * NL;
  float maskf[8];
#pragma unroll
  for (int k = 0; k < 8; ++k) maskf[k] = 0.f;
  float cur[8];
#pragma unroll
  for (int k = 0; k < 8; ++k) cur[k] = base[lane + 64 * k];

  for (int t = 0; t < NT; ++t) {
    float nxt[8] = {0.f, 0.f, 0.f, 0.f, 0.f, 0.f, 0.f, 0.f};
    if (t + 1 < NT) {
      const float* nr = base + (size_t)(t + 1) * NL;
#pragma unroll
      for (int k = 0; k < 8; ++k) nxt[k] = nr[lane + 64 * k];
    }
    float e[8];
    float psum = 0.f;
    float mval = -3.4e38f;
    int midx = 0x7fffffff;
#pragma unroll
    for (int k = 0; k < 8; ++k) {
      float v = cur[k] - maskf[k] * 1000000.0f;
      e[k] = __expf(v);          // masked -> exp(-1e6) = 0 exactly
      psum += e[k];
      int idx = lane + 64 * k;
      if (v > mval || (v == mval && idx < midx)) { mval = v; midx = idx; }
    }
#pragma unroll
    for (int off = 32; off > 0; off >>= 1) {
      float ov = __shfl_xor(mval, off);
      int oi = __shfl_xor(midx, off);
      float ps = __shfl_xor(psum, off);
      psum += ps;
      if (ov > mval || (ov == mval && oi < midx)) { mval = ov; midx = oi; }
    }
    const float inv = 1.0f / psum;
    float* orow = base + (size_t)t * NL;
#pragma unroll
    for (int k = 0; k < 8; ++k) orow[lane + 64 * k] = e[k] * inv;
#pragma unroll
    for (int k = 0; k < 8; ++k)
      if (lane + 64 * k == midx) maskf[k] += 1.0f;
#pragma unroll
    for (int k = 0; k < 8; ++k) cur[k] = nxt[k];
  }
}

extern "C" void kernel_launch(void* const* d_in, const int* in_sizes, int n_in,
                              void* d_out, int out_size, void* d_ws, size_t ws_size,
                              hipStream_t stream) {
  const float* dec_outputs = (const float*)d_in[0];  // [B,T,H]
  const float* enc_outputs = (const float*)d_in[1];  // [B,L,H]
  const float* W1 = (const float*)d_in[3];
  const float* b1 = (const float*)d_in[4];
  const float* W2 = (const float*)d_in[5];
  const float* b2 = (const float*)d_in[6];
  const float* V  = (const float*)d_in[7];
  const float* bV = (const float*)d_in[8];
  float* out = (float*)d_out;  // [B,T,L] f32

  // workspace: [svbv pad 256B][Ed 134MB][Ee 134MB]
  float* svbv = (float*)d_ws;
  float* Ed = (float*)((char*)d_ws + 256);
  float* Ee = Ed + (size_t)NB * NT * NU;

  hipLaunchKernelGGL(k_sumv, dim3(1), dim3(256), 0, stream, V, bV, svbv);
  hipLaunchKernelGGL(k_proj_mfma, dim3(NU / 128, (NB * NT) / 128), dim3(256), 0, stream,
                     dec_outputs, W1, b1, Ed);
  hipLaunchKernelGGL(k_proj_mfma, dim3(NU / 128, (NB * NL) / 128), dim3(256), 0, stream,
                     enc_outputs, W2, b2, Ee);
  hipLaunchKernelGGL(k_score, dim3(NL / 64, NT / 64, NB), dim3(256), 0, stream,
                     Ed, Ee, V, svbv, out);
  hipLaunchKernelGGL(k_seq, dim3(NB), dim3(64), 0, stream, out);
}

// Round 15
// 2308.654 us; speedup vs baseline: 1.2988x; 1.0141x over previous
//
#include <hip/hip_runtime.h>
#include <cstdint>

#define NB 128
#define NT 512
#define NL 512
#define NH 512
#define NU 512

// 2*log2(e): tanh(x) = 1 - 2/(exp2(K2E*x)+1); exp2 hoisted into the GEMM epilogue.
static constexpr float K2E = 2.8853900817779268f;

typedef _Float16 h16;
typedef h16 half8 __attribute__((ext_vector_type(8)));
typedef h16 half4 __attribute__((ext_vector_type(4)));
typedef float f32x4 __attribute__((ext_vector_type(4)));

// ---------------------------------------------------------------- K0: sum(V)+bV
__global__ __launch_bounds__(256) void k_sumv(const float* __restrict__ V,
                                              const float* __restrict__ bV,
                                              float* __restrict__ svbv) {
  __shared__ float red[256];
  int tid = threadIdx.x;
  red[tid] = V[tid] + V[tid + 256];
  __syncthreads();
  for (int off = 128; off > 0; off >>= 1) {
    if (tid < off) red[tid] += red[tid + off];
    __syncthreads();
  }
  if (tid == 0) svbv[0] = red[0] + bV[0];
}

// ------------------- K_prep: W [k][n] f32 -> WhT, WlT [n][k] fp16 (split hi/lo)
// 64x64 tiles via LDS transpose: coalesced read AND coalesced write. Runs once
// per W matrix (~512 KB out) -- removes the per-block re-transpose/re-split
// that dominated R14's k_proj staging.
__global__ __launch_bounds__(256) void k_prep(const float* __restrict__ W,
                                              h16* __restrict__ WhT,
                                              h16* __restrict__ WlT) {
  __shared__ float t[64][65];
  const int tid = threadIdx.x;
  const int k0 = blockIdx.y * 64;
  const int n0 = blockIdx.x * 64;
  const int r = tid >> 4, c4 = (tid & 15) * 4;   // 16 rows per pass, 4 cols/thread
#pragma unroll
  for (int p = 0; p < 4; ++p) {
    int k = r + p * 16;
    float4 v = *(const float4*)(W + (size_t)(k0 + k) * NU + n0 + c4);
    t[c4 + 0][k] = v.x;
    t[c4 + 1][k] = v.y;
    t[c4 + 2][k] = v.z;
    t[c4 + 3][k] = v.w;
  }
  __syncthreads();
#pragma unroll
  for (int p = 0; p < 4; ++p) {
    int n = r + p * 16;
    half4 h, l;
    float vv[4] = {t[n][c4 + 0], t[n][c4 + 1], t[n][c4 + 2], t[n][c4 + 3]};
    h.x = (h16)vv[0]; l.x = (h16)(vv[0] - (float)h.x);
    h.y = (h16)vv[1]; l.y = (h16)(vv[1] - (float)h.y);
    h.z = (h16)vv[2]; l.z = (h16)(vv[2] - (float)h.z);
    h.w = (h16)vv[3]; l.w = (h16)(vv[3] - (float)h.w);
    *(half4*)(WhT + (size_t)(n0 + n) * NH + k0 + c4) = h;
    *(half4*)(WlT + (size_t)(n0 + n) * NH + k0 + c4) = l;
  }
}

// --------------------- K1/K2: out = exp2(K2E*(A@W + bias)) via fp16x3 MFMA
// R15: B-fragments load DIRECTLY from precomputed WhT/WlT (L2-resident 512 KB
// each, [n][k] fp16) -- no W LDS staging, no scatter writes, no per-block
// converts. LDS holds only Ah/Al (20.5 KB). Same fragment mapping as R14
// (passed): A-frag lane l = X[l&15][8*(l>>4)+j]; C/D col=lane&15,
// row=4*(lane>>4)+reg.
#define PSTR 40
__global__ __launch_bounds__(256) void k_proj_mfma(const float* __restrict__ A,
                                                   const h16* __restrict__ WhT,
                                                   const h16* __restrict__ WlT,
                                                   const float* __restrict__ bias,
                                                   float* __restrict__ out) {
  __shared__ __align__(16) h16 Ah[128 * PSTR];   // 10 KB each
  __shared__ __align__(16) h16 Al[128 * PSTR];
  const int tid = threadIdx.x;
  const int m0 = blockIdx.y * 128;
  const int n0 = blockIdx.x * 128;
  const int lane = tid & 63;
  const int wid = tid >> 6;
  const int wm = (wid >> 1) * 64;    // wave m-offset in tile
  const int wn = (wid & 1) * 64;     // wave n-offset in tile
  const int fr = lane & 15;          // fragment row index
  const int fg = lane >> 4;          // fragment k-granule (8 elems)
  const int ar = tid >> 1, ak = (tid & 1) * 16;      // A staging: row, k-offset

  f32x4 acc[4][4];
#pragma unroll
  for (int tm = 0; tm < 4; ++tm)
#pragma unroll
    for (int tn = 0; tn < 4; ++tn) acc[tm][tn] = (f32x4){0.f, 0.f, 0.f, 0.f};

#pragma unroll 1
  for (int kc = 0; kc < 16; ++kc) {
    // ---- stage A tile 128x32 f32 -> fp16 hi/lo, [m][k] layout
#pragma unroll
    for (int q = 0; q < 4; ++q) {
      float4 v = *(const float4*)(A + (size_t)(m0 + ar) * NH + kc * 32 + ak + 4 * q);
      half4 h, l;
      h.x = (h16)v.x; l.x = (h16)(v.x - (float)h.x);
      h.y = (h16)v.y; l.y = (h16)(v.y - (float)h.y);
      h.z = (h16)v.z; l.z = (h16)(v.z - (float)h.z);
      h.w = (h16)v.w; l.w = (h16)(v.w - (float)h.w);
      *(half4*)(Ah + ar * PSTR + ak + 4 * q) = h;
      *(half4*)(Al + ar * PSTR + ak + 4 * q) = l;
    }
    __syncthreads();
    // ---- B fragments direct from global (L2-resident W^T fp16)
    half8 bh[4], bl[4];
#pragma unroll
    for (int tn = 0; tn < 4; ++tn) {
      size_t boff = (size_t)(n0 + wn + tn * 16 + fr) * NH + kc * 32 + 8 * fg;
      bh[tn] = *(const half8*)(WhT + boff);
      bl[tn] = *(const half8*)(WlT + boff);
    }
#pragma unroll
    for (int tm = 0; tm < 4; ++tm) {
      half8 ah = *(const half8*)(Ah + (wm + tm * 16 + fr) * PSTR + 8 * fg);
      half8 al = *(const half8*)(Al + (wm + tm * 16 + fr) * PSTR + 8 * fg);
#pragma unroll
      for (int tn = 0; tn < 4; ++tn) {
        acc[tm][tn] = __builtin_amdgcn_mfma_f32_16x16x32_f16(ah, bh[tn], acc[tm][tn], 0, 0, 0);
        acc[tm][tn] = __builtin_amdgcn_mfma_f32_16x16x32_f16(ah, bl[tn], acc[tm][tn], 0, 0, 0);
        acc[tm][tn] = __builtin_amdgcn_mfma_f32_16x16x32_f16(al, bh[tn], acc[tm][tn], 0, 0, 0);
      }
    }
    __syncthreads();
  }
  // ---- epilogue: D[row=4*fg+reg][col=fr] per tile; exp2(K2E*(acc+bias))
#pragma unroll
  for (int tn = 0; tn < 4; ++tn) {
    const int gn = n0 + wn + tn * 16 + fr;
    const float bsv = bias[gn];
#pragma unroll
    for (int tm = 0; tm < 4; ++tm) {
#pragma unroll
      for (int rg = 0; rg < 4; ++rg) {
        int gm = m0 + wm + tm * 16 + 4 * fg + rg;
        out[(size_t)gm * NU + gn] =
            __builtin_amdgcn_exp2f(K2E * (acc[tm][tn][rg] + bsv));
      }
    }
  }
}

// ---------------------------------------------- K3: S[b,t,l] = base - 2*sum_u V*rc
// R10/R13/R14 version (measured best ~1.53-1.65 ms, VGPR 68, VALUBusy 91%).
__global__ __launch_bounds__(256) void k_score(const float* __restrict__ Ed,
                                               const float* __restrict__ Ee,
                                               const float* __restrict__ Vv,
                                               const float* __restrict__ svbv,
                                               float* __restrict__ out) {
  __shared__ float dpl[64 * 32];   // 8 KB, swizzled 16B granules
  __shared__ float epl[64 * 32];   // 8 KB
  const int tid = threadIdx.x;
  const int b = blockIdx.z;
  const int t0 = blockIdx.y * 64;
  const int l0 = blockIdx.x * 64;
  const int ti = tid & 15;          // t micro group (4 rows)
  const int lj = tid >> 4;          // l micro group (4 cols)
  const int tt = tid & 63;          // staging row
  const int g0 = (tid >> 6) * 2;    // staging granules g0, g0+1
  const float* Edb = Ed + ((size_t)b * NT + t0) * NU;
  const float* Eeb = Ee + ((size_t)b * NL + l0) * NU;
  const int sw = (tt ^ (tt >> 3)) & 7;
  const int pos0 = tt * 32 + 4 * ((g0 + 0) ^ sw);
  const int pos1 = tt * 32 + 4 * ((g0 + 1) ^ sw);
  const size_t srow = (size_t)tt * NU;

  float acc[4][4];
#pragma unroll
  for (int a = 0; a < 4; ++a)
#pragma unroll
    for (int c = 0; c < 4; ++c) acc[a][c] = 0.f;

  // prologue: stage chunk 0
  {
    float4 d0 = *(const float4*)(Edb + srow + 4 * g0);
    float4 d1 = *(const float4*)(Edb + srow + 4 * g0 + 4);
    float4 e0 = *(const float4*)(Eeb + srow + 4 * g0);
    float4 e1 = *(const float4*)(Eeb + srow + 4 * g0 + 4);
    *(float4*)(dpl + pos0) = d0;
    *(float4*)(dpl + pos1) = d1;
    *(float4*)(epl + pos0) = e0;
    *(float4*)(epl + pos1) = e1;
  }
  __syncthreads();

#pragma unroll 1
  for (int c = 0; c < 16; ++c) {
    // issue next-chunk global loads first (latency hidden under compute)
    float4 pd0, pd1, pe0, pe1;
    if (c < 15) {
      const int uc = (c + 1) * 32;
      pd0 = *(const float4*)(Edb + srow + uc + 4 * g0);
      pd1 = *(const float4*)(Edb + srow + uc + 4 * g0 + 4);
      pe0 = *(const float4*)(Eeb + srow + uc + 4 * g0);
      pe1 = *(const float4*)(Eeb + srow + uc + 4 * g0 + 4);
    }
#pragma unroll 1
    for (int g8 = 0; g8 < 4; ++g8) {
      // wave-uniform V loads -> scalar (SGPR) operands
      const float* vb = Vv + c * 32 + g8 * 8;
      const float v0 = vb[0], v1 = vb[1], v2 = vb[2], v3 = vb[3];
      const float v4_ = vb[4], v5 = vb[5], v6 = vb[6], v7 = vb[7];
      float4 bLo[4], bHi[4];
#pragma unroll
      for (int r = 0; r < 4; ++r) {
        int rowb = 4 * lj + r;
        int swb = (rowb ^ (rowb >> 3)) & 7;
        bLo[r] = *(const float4*)(epl + rowb * 32 + 4 * ((2 * g8 + 0) ^ swb));
        bHi[r] = *(const float4*)(epl + rowb * 32 + 4 * ((2 * g8 + 1) ^ swb));
      }
#pragma unroll
      for (int a = 0; a < 4; ++a) {
        int rowa = 4 * ti + a;
        int swa = (rowa ^ (rowa >> 3)) & 7;
        float4 aLo = *(const float4*)(dpl + rowa * 32 + 4 * ((2 * g8 + 0) ^ swa));
        float4 aHi = *(const float4*)(dpl + rowa * 32 + 4 * ((2 * g8 + 1) ^ swa));
#pragma unroll
        for (int cc = 0; cc < 4; ++cc) {
          const float* bp = (const float*)&bLo[cc];
          const float* bh = (const float*)&bHi[cc];
          float d0 = fmaf(aLo.x, bp[0], 1.0f);
          float d1 = fmaf(aLo.y, bp[1], 1.0f);
          float d2 = fmaf(aLo.z, bp[2], 1.0f);
          float d3 = fmaf(aLo.w, bp[3], 1.0f);
          float d4 = fmaf(aHi.x, bh[0], 1.0f);
          float d5 = fmaf(aHi.y, bh[1], 1.0f);
          float d6 = fmaf(aHi.z, bh[2], 1.0f);
          float d7 = fmaf(aHi.w, bh[3], 1.0f);
          float d01 = d0 * d1, d23 = d2 * d3, d45 = d4 * d5, d67 = d6 * d7;
          float n01 = fmaf(v0, d1, v1 * d0);
          float n23 = fmaf(v2, d3, v3 * d2);
          float n45 = fmaf(v4_, d5, v5 * d4);
          float n67 = fmaf(v6, d7, v7 * d6);
          float n03 = fmaf(n01, d23, n23 * d01);
          float d03 = d01 * d23;
          float n47 = fmaf(n45, d67, n67 * d45);
          float d47 = d45 * d67;
          float num = fmaf(n03, d47, n47 * d03);
          float den = d03 * d47;
          acc[a][cc] = fmaf(num, __builtin_amdgcn_rcpf(den), acc[a][cc]);
        }
      }
    }
    __syncthreads();   // all reads of this chunk done (uniform trip count)
    if (c < 15) {
      *(float4*)(dpl + pos0) = pd0;
      *(float4*)(dpl + pos1) = pd1;
      *(float4*)(epl + pos0) = pe0;
      *(float4*)(epl + pos1) = pe1;
      __syncthreads(); // writes visible (uniform)
    }
  }

  const float base = svbv[0];  // sum(V) + bV
#pragma unroll
  for (int a = 0; a < 4; ++a) {
    size_t orow = ((size_t)b * NT + t0 + 4 * ti + a) * NL + l0 + 4 * lj;
    float4 ov;
    ov.x = base - 2.f * acc[a][0];
    ov.y = base - 2.f * acc[a][1];
    ov.z = base - 2.f * acc[a][2];
    ov.w = base - 2.f * acc[a][3];
    *(float4*)(out + orow) = ov;
  }
}

// ------------------------- K4: sequential mask/softmax/argmax, in-place on d_out
__global__ __launch_bounds__(64) void k_seq(float* __restrict__ out) {
  const int b = blockIdx.x;
  const int lane = threadIdx.x;
  float* base = out + (size_t)b * NT * NL;
  float maskf[8];
#pragma unroll
  for (int k = 0; k < 8; ++k) maskf[k] = 0.f;
  float cur[8];
#pragma unroll
  for (int k = 0; k < 8; ++k) cur[k] = base[lane + 64 * k];

  for (int t = 0; t < NT; ++t) {
    float nxt[8] = {0.f, 0.f, 0.f, 0.f, 0.f, 0.f, 0.f, 0.f};
    if (t + 1 < NT) {
      const float* nr = base + (size_t)(t + 1) * NL;
#pragma unroll
      for (int k = 0; k < 8; ++k) nxt[k] = nr[lane + 64 * k];
    }
    float e[8];
    float psum = 0.f;
    float mval = -3.4e38f;
    int midx = 0x7fffffff;
#pragma unroll
    for (int k = 0; k < 8; ++k) {
      float v = cur[k] - maskf[k] * 1000000.0f;
      e[k] = __expf(v);          // masked -> exp(-1e6) = 0 exactly
      psum += e[k];
      int idx = lane + 64 * k;
      if (v > mval || (v == mval && idx < midx)) { mval = v; midx = idx; }
    }
#pragma unroll
    for (int off = 32; off > 0; off >>= 1) {
      float ov = __shfl_xor(mval, off);
      int oi = __shfl_xor(midx, off);
      float ps = __shfl_xor(psum, off);
      psum += ps;
      if (ov > mval || (ov == mval && oi < midx)) { mval = ov; midx = oi; }
    }
    const float inv = 1.0f / psum;
    float* orow = base + (size_t)t * NL;
#pragma unroll
    for (int k = 0; k < 8; ++k) orow[lane + 64 * k] = e[k] * inv;
#pragma unroll
    for (int k = 0; k < 8; ++k)
      if (lane + 64 * k == midx) maskf[k] += 1.0f;
#pragma unroll
    for (int k = 0; k < 8; ++k) cur[k] = nxt[k];
  }
}

extern "C" void kernel_launch(void* const* d_in, const int* in_sizes, int n_in,
                              void* d_out, int out_size, void* d_ws, size_t ws_size,
                              hipStream_t stream) {
  const float* dec_outputs = (const float*)d_in[0];  // [B,T,H]
  const float* enc_outputs = (const float*)d_in[1];  // [B,L,H]
  const float* W1 = (const float*)d_in[3];
  const float* b1 = (const float*)d_in[4];
  const float* W2 = (const float*)d_in[5];
  const float* b2 = (const float*)d_in[6];
  const float* V  = (const float*)d_in[7];
  const float* bV = (const float*)d_in[8];
  float* out = (float*)d_out;  // [B,T,L] f32

  // workspace: [svbv 256B][Ed 134.2MB][Ee 134.2MB][W1hT|W1lT|W2hT|W2lT 4x512KB]
  float* svbv = (float*)d_ws;
  float* Ed = (float*)((char*)d_ws + 256);
  float* Ee = Ed + (size_t)NB * NT * NU;
  h16* W1hT = (h16*)(Ee + (size_t)NB * NL * NU);
  h16* W1lT = W1hT + (size_t)NH * NU;
  h16* W2hT = W1lT + (size_t)NH * NU;
  h16* W2lT = W2hT + (size_t)NH * NU;

  hipLaunchKernelGGL(k_sumv, dim3(1), dim3(256), 0, stream, V, bV, svbv);
  hipLaunchKernelGGL(k_prep, dim3(NU / 64, NH / 64), dim3(256), 0, stream,
                     W1, W1hT, W1lT);
  hipLaunchKernelGGL(k_prep, dim3(NU / 64, NH / 64), dim3(256), 0, stream,
                     W2, W2hT, W2lT);
  hipLaunchKernelGGL(k_proj_mfma, dim3(NU / 128, (NB * NT) / 128), dim3(256), 0, stream,
                     dec_outputs, W1hT, W1lT, b1, Ed);
  hipLaunchKernelGGL(k_proj_mfma, dim3(NU / 128, (NB * NL) / 128), dim3(256), 0, stream,
                     enc_outputs, W2hT, W2lT, b2, Ee);
  hipLaunchKernelGGL(k_score, dim3(NL / 64, NT / 64, NB), dim3(256), 0, stream,
                     Ed, Ee, V, svbv, out);
  hipLaunchKernelGGL(k_seq, dim3(NB), dim3(64), 0, stream, out);
}